// Round 5
// baseline (156.070 us; speedup 1.0000x reference)
//
#include <hip/hip_runtime.h>
#include <math.h>

#define EPS  1e-6f
#define DD   256
#define NSUP 5
#define NQ   8
#define SEQ  13
#define L2E  1.44269504088896f
#define LN2  0.693147180559945f
#define NEP  2048            // episodes
#define NROW 16384           // NEP*NQ query rows
#define NCOL 2048            // anchor columns

typedef short bf16x8 __attribute__((ext_vector_type(8)));
typedef float f32x4  __attribute__((ext_vector_type(4)));

__device__ __forceinline__ ushort f2bf(float f) {
  union { float f; unsigned u; } v; v.f = f;
  unsigned r = v.u + 0x7FFFu + ((v.u >> 16) & 1u);   // round-to-nearest-even
  return (ushort)(r >> 16);
}
__device__ __forceinline__ float bf2f(short u) {
  union { unsigned u; float f; } v; v.u = ((unsigned)(unsigned short)u) << 16;
  return v.f;
}

// ---------------------------------------------------------------------------
// prep: anchors/queries in MFMA-fragment-SWIZZLED order (coalesced fragment
// loads in main): element (c,d) -> ushort index ((T*8+kk)*64 + quad*16 + lc)*8
// + j with T=c>>4, lc=c&15, kk=d>>5, quad=(d>>3)&3, j=d&7.
// cb[c] = -log2(e) * (sum(a^2) - 2*eps*sum(a)); row-constant cq cancels.
// ---------------------------------------------------------------------------
__global__ __launch_bounds__(256) void proto_prep(
    const float* __restrict__ x, float* __restrict__ cb,
    ushort* __restrict__ Asw, ushort* __restrict__ Qsw,
    float* __restrict__ accum, int* __restrict__ counter) {
  const int n = blockIdx.x, d = threadIdx.x;
  if (n == 0 && d == 0) { accum[0] = 0.f; accum[1] = 0.f; counter[0] = 0; }
  const float* xr = x + (size_t)n * SEQ * DD;

  const int kk = d >> 5, quad = (d >> 3) & 3, j = d & 7;
  const size_t dpart = (size_t)kk * 64 + quad * 16;   // within-T part from d

  float a = 0.f;
  #pragma unroll
  for (int s = 0; s < NSUP; ++s) a += xr[s * DD + d];
  a *= 0.2f;
  Asw[(((size_t)(n >> 4) * 8 * 64) + dpart + (n & 15)) * 8 + j] = f2bf(a);

  float s1 = a, s2 = a * a;
  #pragma unroll
  for (int off = 32; off; off >>= 1) {
    s1 += __shfl_xor(s1, off);
    s2 += __shfl_xor(s2, off);
  }
  __shared__ float red[8];
  const int wid = d >> 6, lane = d & 63;
  if (lane == 0) { red[wid] = s1; red[wid + 4] = s2; }
  __syncthreads();
  if (d == 0) {
    float t1 = red[0] + red[1] + red[2] + red[3];
    float t2 = red[4] + red[5] + red[6] + red[7];
    cb[n] = -L2E * (t2 - 2.f * EPS * t1);
  }
  #pragma unroll
  for (int s = 0; s < NQ; ++s) {
    const int row = n * NQ + s;
    Qsw[(((size_t)(row >> 4) * 8 * 64) + dpart + (row & 15)) * 8 + j]
        = f2bf(xr[(NSUP + s) * DD + d]);
  }
}

// ---------------------------------------------------------------------------
// main: 512 blocks x 512 threads (8 waves). Block = 32 rows; wave w owns col
// stripe [w*256,+256) = 16 tiles. 4 waves/SIMD resident (2 blocks/CU).
// Hot loop per C slot: 9 VALU (no label tracking — label logit recomputed in
// a post-pass bf16 dot with identical rounding). Ping-pong B prefetch.
// Cross-lane (16) merge -> LDS merge across 8 stripes (ascending col order)
// -> per-block atomics -> counter-based finalize. MFMA layouts (verified):
// A m=lane&15,k=quad*8+j ; B n=lane&15,k=quad*8+j ; C col=lane&15,row=quad*4+reg.
// ---------------------------------------------------------------------------
__global__ __launch_bounds__(512, 4) void proto_main(
    const ushort* __restrict__ Qsw, const ushort* __restrict__ Asw,
    const float* __restrict__ cb, const int* __restrict__ label,
    float* __restrict__ accum, int* __restrict__ counter,
    float* __restrict__ out) {
  const int tid  = threadIdx.x;
  const int wid  = tid >> 6, lane = tid & 63;
  const int quad = lane >> 4, lcol = lane & 15;
  const int r0   = blockIdx.x * 32;

  const bf16x8* qb = (const bf16x8*)Qsw;
  const bf16x8* bb = (const bf16x8*)Asw;

  // resident A fragments: 2 row-sets x 8 K-chunks (coalesced loads)
  bf16x8 af[2][8];
  #pragma unroll
  for (int set = 0; set < 2; ++set) {
    const size_t base = ((size_t)((r0 >> 4) + set) * 8) * 64 + lane;
    #pragma unroll
    for (int kk = 0; kk < 8; ++kk) af[set][kk] = qb[base + (size_t)kk * 64];
  }

  float m[2][4], s[2][4];
  int   bi[2][4];
  #pragma unroll
  for (int set = 0; set < 2; ++set)
    #pragma unroll
    for (int i = 0; i < 4; ++i) {
      m[set][i] = -1e30f; s[set][i] = 0.f; bi[set][i] = 0x7fffffff;
    }

  auto process = [&](int T, bf16x8* B) {
    f32x4 c0 = {0.f, 0.f, 0.f, 0.f}, c1 = {0.f, 0.f, 0.f, 0.f};
    #pragma unroll
    for (int kk = 0; kk < 8; ++kk) {
      c0 = __builtin_amdgcn_mfma_f32_16x16x32_bf16(af[0][kk], B[kk], c0, 0, 0, 0);
      c1 = __builtin_amdgcn_mfma_f32_16x16x32_bf16(af[1][kk], B[kk], c1, 0, 0, 0);
    }
    const int   colIdx = T * 16 + lcol;
    const float cbv    = cb[colIdx];       // 64-B broadcast segment
    #pragma unroll
    for (int set = 0; set < 2; ++set) {
      #pragma unroll
      for (int i = 0; i < 4; ++i) {
        float cv = (set == 0) ? c0[i] : c1[i];
        float v2 = fmaf(cv, 2.f * L2E, cbv);     // log2-frame shifted logit
        float dv = v2 - m[set][i];
        bool  gt = dv > 0.f;
        float e  = exp2f(-fabsf(dv));            // single non-unit exp factor
        s[set][i]  = fmaf(s[set][i], gt ? e : 1.f, gt ? 1.f : e);
        m[set][i]  = fmaxf(m[set][i], v2);
        bi[set][i] = gt ? colIdx : bi[set][i];   // strict >: first max wins
      }
    }
  };

  const int T0 = wid * 16;
  bf16x8 buf0[8], buf1[8];
  #pragma unroll
  for (int kk = 0; kk < 8; ++kk)
    buf0[kk] = bb[((size_t)T0 * 8 + (size_t)kk) * 64 + lane];

  #pragma unroll 1
  for (int t = 0; t < 16; t += 2) {
    {
      const int Tn = T0 + t + 1;                             // always valid
      #pragma unroll
      for (int kk = 0; kk < 8; ++kk)
        buf1[kk] = bb[((size_t)Tn * 8 + (size_t)kk) * 64 + lane];
    }
    process(T0 + t, buf0);
    {
      const int Tn = (t + 2 < 16) ? T0 + t + 2 : T0 + t + 1; // clamp tail
      #pragma unroll
      for (int kk = 0; kk < 8; ++kk)
        buf0[kk] = bb[((size_t)Tn * 8 + (size_t)kk) * 64 + lane];
    }
    process(T0 + t + 1, buf1);
  }

  // merge across the 16 lanes sharing rows (cols differ)
  #pragma unroll
  for (int mask = 1; mask < 16; mask <<= 1) {
    #pragma unroll
    for (int set = 0; set < 2; ++set)
      #pragma unroll
      for (int i = 0; i < 4; ++i) {
        float om = __shfl_xor(m[set][i], mask);
        float os = __shfl_xor(s[set][i], mask);
        int   oi = __shfl_xor(bi[set][i], mask);
        float nm = fmaxf(m[set][i], om);
        s[set][i] = s[set][i] * exp2f(m[set][i] - nm) + os * exp2f(om - nm);
        bool better = (om > m[set][i]) || (om == m[set][i] && oi < bi[set][i]);
        bi[set][i] = better ? oi : bi[set][i];
        m[set][i]  = nm;
      }
  }

  __shared__ float sm[8][32], ssh[8][32], slab[32];
  __shared__ int   sbi[8][32];
  if (lcol == 0) {
    #pragma unroll
    for (int set = 0; set < 2; ++set)
      #pragma unroll
      for (int i = 0; i < 4; ++i) {
        int rl = set * 16 + quad * 4 + i;
        sm[wid][rl] = m[set][i]; ssh[wid][rl] = s[set][i]; sbi[wid][rl] = bi[set][i];
      }
  }

  // label-logit post-pass: group g (16 lanes) computes bf16 dot for row r0+g
  {
    const int g = tid >> 4, l = tid & 15;
    const int row = r0 + g;
    const int lab = label[row >> 3];
    const size_t qc = ((size_t)(row >> 4) * 8 + (l >> 1)) * 64
                    + (size_t)((2 * l) & 3) * 16 + (row & 15);
    const size_t ac = ((size_t)(lab >> 4) * 8 + (l >> 1)) * 64
                    + (size_t)((2 * l) & 3) * 16 + (lab & 15);
    bf16x8 q0 = qb[qc], q1 = qb[qc + 16];
    bf16x8 a0 = bb[ac], a1 = bb[ac + 16];
    float dot = 0.f;
    #pragma unroll
    for (int j = 0; j < 8; ++j) {
      dot = fmaf(bf2f(q0[j]), bf2f(a0[j]), dot);
      dot = fmaf(bf2f(q1[j]), bf2f(a1[j]), dot);
    }
    #pragma unroll
    for (int mask = 1; mask < 16; mask <<= 1) dot += __shfl_xor(dot, mask);
    if (l == 0) slab[g] = fmaf(dot, 2.f * L2E, cb[lab]);   // shifted label logit
  }
  __syncthreads();

  if (tid < 32) {
    float mm = sm[0][tid], sv = ssh[0][tid];
    int   b  = sbi[0][tid];
    #pragma unroll
    for (int w = 1; w < 8; ++w) {            // stripes in ascending col order
      float om = sm[w][tid], os = ssh[w][tid];
      int   oi = sbi[w][tid];
      float nm = fmaxf(mm, om);
      sv = sv * exp2f(mm - nm) + os * exp2f(om - nm);
      bool better = (om > mm) || (om == mm && oi < b);
      b = better ? oi : b;
      mm = nm;
    }
    const int row = r0 + tid;
    const int lb  = label[row >> 3];
    float loss = LN2 * (mm + log2f(sv) - slab[tid]);
    float corr = (b == lb) ? 1.f : 0.f;
    #pragma unroll
    for (int mask = 16; mask; mask >>= 1) {   // xor stays closed in lanes 0..31
      loss += __shfl_xor(loss, mask);
      corr += __shfl_xor(corr, mask);
    }
    if (tid == 0) {
      atomicAdd(&accum[0], loss);
      atomicAdd(&accum[1], corr);
      __threadfence();
      if (atomicAdd(counter, 1) == (int)gridDim.x - 1) {
        out[0] = atomicAdd(&accum[0], 0.f) / (float)NROW;   // coherent reads
        out[1] = atomicAdd(&accum[1], 0.f) * 100.f / (float)NROW;
      }
    }
  }
}

// ---------------------------------------------------------------------------
extern "C" void kernel_launch(void* const* d_in, const int* in_sizes, int n_in,
                              void* d_out, int out_size, void* d_ws, size_t ws_size,
                              hipStream_t stream) {
  const float* x     = (const float*)d_in[0];
  const int*   label = (const int*)d_in[1];
  float* out = (float*)d_out;

  // ws layout (floats): [0:2) accum | [2] counter | [16,16+NCOL) cb |
  //                     Asw (NCOL*DD ushort) | Qsw (NROW*DD ushort)
  float*  W       = (float*)d_ws;
  float*  accum   = W;
  int*    counter = (int*)(W + 2);
  float*  cb      = W + 16;
  ushort* Asw     = (ushort*)(cb + NCOL);
  ushort* Qsw     = Asw + (size_t)NCOL * DD;

  hipLaunchKernelGGL(proto_prep, dim3(NEP), dim3(256), 0, stream,
                     x, cb, Asw, Qsw, accum, counter);
  hipLaunchKernelGGL(proto_main, dim3(NROW / 32), dim3(512), 0, stream,
                     Qsw, Asw, cb, label, accum, counter, out);
}